// Round 9
// baseline (691.102 us; speedup 1.0000x reference)
//
#include <hip/hip_runtime.h>
#include <cstddef>

#define NH 32
#define TSEQ 2048

typedef short bf16x8_t __attribute__((ext_vector_type(8)));
typedef float f32x4_t  __attribute__((ext_vector_type(4)));

__device__ __forceinline__ float b2f(short u) {
  unsigned v = ((unsigned)(unsigned short)u) << 16;
  return __builtin_bit_cast(float, v);
}
__device__ __forceinline__ short f2b(float f) {
  unsigned u = __builtin_bit_cast(unsigned, f);
  u = u + 0x7fffu + ((u >> 16) & 1u);   // RNE; inputs never NaN/Inf here
  return (short)(u >> 16);
}

// async global->LDS, 16B per lane; LDS dest is wave-uniform (HW writes base + lane*16)
__device__ __forceinline__ void gload16(const short* g, short* l) {
  __builtin_amdgcn_global_load_lds(
      (const __attribute__((address_space(1))) void*)g,
      (__attribute__((address_space(3))) void*)l, 16, 0, 0);
}

// ------------- fp32 -> bf16 row-major convert (for h) ---------------------------------
__global__ __launch_bounds__(256) void conv_full(
    const float* __restrict__ in, short* __restrict__ out, long long n8) {
  long long g = (long long)blockIdx.x * 256 + threadIdx.x;
  if (g >= n8) return;
  const float* p = in + g * 8;
  float4 a = *reinterpret_cast<const float4*>(p);
  float4 b = *reinterpret_cast<const float4*>(p + 4);
  bf16x8_t v;
  v[0] = f2b(a.x); v[1] = f2b(a.y); v[2] = f2b(a.z); v[3] = f2b(a.w);
  v[4] = f2b(b.x); v[5] = f2b(b.y); v[6] = f2b(b.z); v[7] = f2b(b.w);
  *reinterpret_cast<bf16x8_t*>(out + g * 8) = v;
}

// ------------- fused transpose + fp32->bf16: in[R][ldin] (submatrix R x C) -> out[C][R]
__global__ __launch_bounds__(256) void tconv(
    const float* __restrict__ in, short* __restrict__ out, int R, int ldin) {
  __shared__ short tile[64][72];
  const int tid = threadIdx.x;
  const int c0 = blockIdx.x * 64, r0 = blockIdx.y * 64;
#pragma unroll
  for (int cc = 0; cc < 2; ++cc) {
    int idx = tid + cc * 256;
    int row = idx >> 3, col = (idx & 7) * 8;
    const float* p = in + (size_t)(r0 + row) * ldin + c0 + col;
    float4 a = *reinterpret_cast<const float4*>(p);
    float4 b = *reinterpret_cast<const float4*>(p + 4);
    short* t = &tile[row][col];
    t[0] = f2b(a.x); t[1] = f2b(a.y); t[2] = f2b(a.z); t[3] = f2b(a.w);
    t[4] = f2b(b.x); t[5] = f2b(b.y); t[6] = f2b(b.z); t[7] = f2b(b.w);
  }
  __syncthreads();
#pragma unroll
  for (int cc = 0; cc < 2; ++cc) {
    int idx = tid + cc * 256;
    int orow = idx >> 3, ocol = (idx & 7) * 8;
    bf16x8_t v;
#pragma unroll
    for (int j = 0; j < 8; ++j) v[j] = tile[ocol + j][orow];
    *reinterpret_cast<bf16x8_t*>(out + (size_t)(c0 + orow) * R + r0 + ocol) = v;
  }
}

// ---------------- GEMM: C[M][ldc] = A[M][K] * Bt[N][K]^T, bf16 in, bf16/f32 out -------
// M%128==0, N%128==0, K%64==0 at call sites. Round-7-verified XOR-swizzled
// global_load_lds staging + NEW round-9 T3-minimum double-buffer: prefetch tile t+1
// into buf[cur^1] BEFORE computing tile t from buf[cur]; ONE barrier per iteration
// (compiler's pre-barrier vmcnt(0) drain now overlaps the whole compute phase).
// Safety: buf[cur^1] was last read in iter t-1, completed before that iter's barrier.
template <bool F32OUT>
__global__ __launch_bounds__(256) void gemm_btt(
    const short* __restrict__ A, const short* __restrict__ Bt,
    void* __restrict__ Cv, int M, int N, int K, int ldc) {
  __shared__ __align__(16) short Alds[2][128][64];
  __shared__ __align__(16) short Blds[2][128][64];
  const int tid = threadIdx.x;
  const int wave = tid >> 6, lane = tid & 63, quad = lane >> 4, l16 = lane & 15;
  const int m0 = blockIdx.y * 128, n0 = blockIdx.x * 128;
  const int wm = (wave >> 1) * 64, wn = (wave & 1) * 64;
  const int lrow = lane >> 3;
  const int lcol = ((lane ^ lrow) & 7) * 8;   // XOR-swizzled source slot (shorts)

  f32x4_t acc[4][4];
#pragma unroll
  for (int i = 0; i < 4; ++i)
#pragma unroll
    for (int j = 0; j < 4; ++j) {
      acc[i][j][0] = 0.f; acc[i][j][1] = 0.f; acc[i][j][2] = 0.f; acc[i][j][3] = 0.f;
    }

  // prologue: stage tile 0 into buf 0
#pragma unroll
  for (int c = 0; c < 4; ++c) {
    int chunk = wave + c * 4;
    int row = chunk * 8 + lrow;
    gload16(A + (size_t)(m0 + row) * K + lcol, &Alds[0][chunk * 8][0]);
    gload16(Bt + (size_t)(n0 + row) * K + lcol, &Blds[0][chunk * 8][0]);
  }
  __syncthreads();

  int cur = 0;
  const int nk = K >> 6;
  for (int t = 0; t < nk; ++t) {
    if (t + 1 < nk) {
      const int kn = (t + 1) << 6;
#pragma unroll
      for (int c = 0; c < 4; ++c) {
        int chunk = wave + c * 4;
        int row = chunk * 8 + lrow;
        gload16(A + (size_t)(m0 + row) * K + kn + lcol, &Alds[cur ^ 1][chunk * 8][0]);
        gload16(Bt + (size_t)(n0 + row) * K + kn + lcol, &Blds[cur ^ 1][chunk * 8][0]);
      }
    }
#pragma unroll
    for (int s = 0; s < 2; ++s) {
      bf16x8_t af[4], bfr[4];
#pragma unroll
      for (int i = 0; i < 4; ++i)
        af[i] = *reinterpret_cast<const bf16x8_t*>(
            &Alds[cur][wm + i * 16 + l16][(((s * 4 + quad) ^ l16) & 7) * 8]);
#pragma unroll
      for (int j = 0; j < 4; ++j)
        bfr[j] = *reinterpret_cast<const bf16x8_t*>(
            &Blds[cur][wn + j * 16 + l16][(((s * 4 + quad) ^ l16) & 7) * 8]);
#pragma unroll
      for (int i = 0; i < 4; ++i)
#pragma unroll
        for (int j = 0; j < 4; ++j)
          acc[i][j] = __builtin_amdgcn_mfma_f32_16x16x32_bf16(af[i], bfr[j], acc[i][j], 0, 0, 0);
    }
    __syncthreads();   // drains vmcnt(0) (next tile resident) + all reads of cur done
    cur ^= 1;
  }
#pragma unroll
  for (int j = 0; j < 4; ++j) {
    int col = n0 + wn + j * 16 + l16;
#pragma unroll
    for (int i = 0; i < 4; ++i) {
      int rowb = m0 + wm + i * 16 + quad * 4;
#pragma unroll
      for (int r = 0; r < 4; ++r) {
        if constexpr (F32OUT) {
          ((float*)Cv)[(size_t)(rowb + r) * ldc + col] = acc[i][j][r];
        } else {
          ((short*)Cv)[(size_t)(rowb + r) * ldc + col] = f2b(acc[i][j][r]);
        }
      }
    }
  }
}

// ------- split-K pure-bf16 GEMM (fused q1+latent), same dbuf structure ----------------
// N=2112: last n-block's B rows OOB-read workspace garbage, epilogue-discarded.
__global__ __launch_bounds__(256) void gemm_skb(
    const short* __restrict__ A, const short* __restrict__ Bt,
    short* __restrict__ Cp, int M, int N, int K, int kchunk) {
  __shared__ __align__(16) short Alds[2][128][64];
  __shared__ __align__(16) short Blds[2][128][64];
  const int tid = threadIdx.x;
  const int wave = tid >> 6, lane = tid & 63, quad = lane >> 4, l16 = lane & 15;
  const int m0 = blockIdx.y * 128, n0 = blockIdx.x * 128;
  const int wm = (wave >> 1) * 64, wn = (wave & 1) * 64;
  const int lrow = lane >> 3;
  const int lcol = ((lane ^ lrow) & 7) * 8;
  const int kb = blockIdx.z * kchunk;

  f32x4_t acc[4][4];
#pragma unroll
  for (int i = 0; i < 4; ++i)
#pragma unroll
    for (int j = 0; j < 4; ++j) {
      acc[i][j][0] = 0.f; acc[i][j][1] = 0.f; acc[i][j][2] = 0.f; acc[i][j][3] = 0.f;
    }

#pragma unroll
  for (int c = 0; c < 4; ++c) {
    int chunk = wave + c * 4;
    int row = chunk * 8 + lrow;
    gload16(A + (size_t)(m0 + row) * K + kb + lcol, &Alds[0][chunk * 8][0]);
    gload16(Bt + (size_t)(n0 + row) * K + kb + lcol, &Blds[0][chunk * 8][0]);
  }
  __syncthreads();

  int cur = 0;
  const int nk = kchunk >> 6;
  for (int t = 0; t < nk; ++t) {
    if (t + 1 < nk) {
      const int kn = kb + ((t + 1) << 6);
#pragma unroll
      for (int c = 0; c < 4; ++c) {
        int chunk = wave + c * 4;
        int row = chunk * 8 + lrow;
        gload16(A + (size_t)(m0 + row) * K + kn + lcol, &Alds[cur ^ 1][chunk * 8][0]);
        gload16(Bt + (size_t)(n0 + row) * K + kn + lcol, &Blds[cur ^ 1][chunk * 8][0]);
      }
    }
#pragma unroll
    for (int s = 0; s < 2; ++s) {
      bf16x8_t af[4], bfr[4];
#pragma unroll
      for (int i = 0; i < 4; ++i)
        af[i] = *reinterpret_cast<const bf16x8_t*>(
            &Alds[cur][wm + i * 16 + l16][(((s * 4 + quad) ^ l16) & 7) * 8]);
#pragma unroll
      for (int j = 0; j < 4; ++j)
        bfr[j] = *reinterpret_cast<const bf16x8_t*>(
            &Blds[cur][wn + j * 16 + l16][(((s * 4 + quad) ^ l16) & 7) * 8]);
#pragma unroll
      for (int i = 0; i < 4; ++i)
#pragma unroll
        for (int j = 0; j < 4; ++j)
          acc[i][j] = __builtin_amdgcn_mfma_f32_16x16x32_bf16(af[i], bfr[j], acc[i][j], 0, 0, 0);
    }
    __syncthreads();
    cur ^= 1;
  }
  short* out = Cp + (size_t)blockIdx.z * M * N;
#pragma unroll
  for (int j = 0; j < 4; ++j) {
    int col = n0 + wn + j * 16 + l16;
    if (col >= N) continue;
#pragma unroll
    for (int i = 0; i < 4; ++i) {
      int rowb = m0 + wm + i * 16 + quad * 4;
#pragma unroll
      for (int r = 0; r < 4; ++r)
        out[(size_t)(rowb + r) * N + col] = f2b(acc[i][j][r]);
    }
  }
}

// ------- reduce-2 + RMSNorm over cols 0..1535 of part [2][2048][2112] bf16 -> qn ------
__global__ __launch_bounds__(256) void rmsnorm1536_r(
    const short* __restrict__ part, const float* __restrict__ g, short* __restrict__ y) {
  const int t = blockIdx.x, tid = threadIdx.x;
  const size_t SL = (size_t)2048 * 2112;
  const short* row = part + (size_t)t * 2112;
  float v[6], ss = 0.f;
#pragma unroll
  for (int i = 0; i < 6; ++i) {
    int col = tid + i * 256;
    v[i] = b2f(row[col]) + b2f(row[SL + col]);
    ss += v[i] * v[i];
  }
#pragma unroll
  for (int off = 1; off < 64; off <<= 1) ss += __shfl_xor(ss, off, 64);
  __shared__ float red[4];
  if ((tid & 63) == 0) red[tid >> 6] = ss;
  __syncthreads();
  float tot = red[0] + red[1] + red[2] + red[3];
  float sc = rsqrtf(tot * (1.0f / 1536.0f) + 1e-6f);
#pragma unroll
  for (int i = 0; i < 6; ++i)
    y[(size_t)t * 1536 + tid + i * 256] = f2b(v[i] * sc * g[tid + i * 256]);
}

// ------- reduce-2 + bias + kv_a RMSNorm (512) + k_pe RoPE (64), cols 1536..2111 --------
__global__ __launch_bounds__(256) void kvnormrope_r(
    const short* __restrict__ part, const float* __restrict__ bkva,
    const float* __restrict__ gkv, const int* __restrict__ pos,
    short* __restrict__ kvn, short* __restrict__ kpe) {
  const int t = blockIdx.x, tid = threadIdx.x;
  const size_t SL = (size_t)2048 * 2112;
  const short* row = part + (size_t)t * 2112 + 1536;
  float v0 = bkva[tid] + b2f(row[tid]) + b2f(row[SL + tid]);
  float v1 = bkva[tid + 256] + b2f(row[tid + 256]) + b2f(row[SL + tid + 256]);
  float ss = v0 * v0 + v1 * v1;
#pragma unroll
  for (int off = 1; off < 64; off <<= 1) ss += __shfl_xor(ss, off, 64);
  __shared__ float red[4];
  if ((tid & 63) == 0) red[tid >> 6] = ss;
  __syncthreads();
  float tot = red[0] + red[1] + red[2] + red[3];
  float sc = rsqrtf(tot * (1.0f / 512.0f) + 1e-6f);
  kvn[(size_t)t * 512 + tid]       = f2b(v0 * sc * gkv[tid]);
  kvn[(size_t)t * 512 + tid + 256] = f2b(v1 * sc * gkv[tid + 256]);
  if (tid < 32) {
    float x1 = bkva[512 + 2 * tid] + b2f(row[512 + 2 * tid]) + b2f(row[SL + 512 + 2 * tid]);
    float x2 = bkva[513 + 2 * tid] + b2f(row[513 + 2 * tid]) + b2f(row[SL + 513 + 2 * tid]);
    float p = (float)pos[t];
    float inv = powf(10000.0f, -(float)tid / 32.0f);
    float f = p * inv;
    float sn = sinf(f), cs = cosf(f);
    kpe[(size_t)t * 64 + 2 * tid]     = f2b(x1 * cs - x2 * sn);
    kpe[(size_t)t * 64 + 2 * tid + 1] = f2b(x1 * sn + x2 * cs);
  }
}

// ---------------- in-place RoPE on q_pe slice of q [T][H*192] -------------------------
__global__ __launch_bounds__(256) void ropeq(short* __restrict__ q, const int* __restrict__ pos) {
  int idx = blockIdx.x * 256 + threadIdx.x;  // T*H*32 pairs
  int i = idx & 31, h = (idx >> 5) & 31, t = idx >> 10;
  size_t base = (size_t)t * 6144 + h * 192 + 128 + 2 * i;
  float x1 = b2f(q[base]), x2 = b2f(q[base + 1]);
  float p = (float)pos[t];
  float inv = powf(10000.0f, -(float)i / 32.0f);
  float f = p * inv;
  float sn = sinf(f), cs = cosf(f);
  q[base]     = f2b(x1 * cs - x2 * sn);
  q[base + 1] = f2b(x1 * sn + x2 * cs);
}

// ---------------- flash attention, balanced causal pairing ----------------------------
// round-9: + defer-max (T13, THR=8): skip alpha-rescale of oacc/l_run when the tile max
// didn't grow by >8 (wave-uniform __all). Exact online-softmax math preserved; P bounded
// by e^8, f32 accumulate.
#define PROC(aq, oacc, m_run, l_run, q0v, diagv, PH)                                    \
  {                                                                                     \
    const int q0_ = (q0v);                                                              \
    const bool diag_ = (diagv);                                                         \
    f32x4_t sacc[4];                                                                    \
    _Pragma("unroll")                                                                   \
    for (int nt = 0; nt < 4; ++nt) {                                                    \
      sacc[nt][0] = 0.f; sacc[nt][1] = 0.f; sacc[nt][2] = 0.f; sacc[nt][3] = 0.f;       \
    }                                                                                   \
    __builtin_amdgcn_s_setprio(1);                                                      \
    _Pragma("unroll")                                                                   \
    for (int nt = 0; nt < 4; ++nt) {                                                    \
      _Pragma("unroll")                                                                 \
      for (int s = 0; s < 6; ++s) {                                                     \
        bf16x8_t bk = *reinterpret_cast<const bf16x8_t*>(                               \
            &Klds[nt * 16 + l16][s * 32 + quad * 8]);                                   \
        sacc[nt] = __builtin_amdgcn_mfma_f32_16x16x32_bf16(aq[s], bk, sacc[nt], 0, 0, 0); \
      }                                                                                 \
    }                                                                                   \
    __builtin_amdgcn_s_setprio(0);                                                      \
    float p_[4][4], mt[4];                                                              \
    _Pragma("unroll")                                                                   \
    for (int r = 0; r < 4; ++r) mt[r] = NEG;                                            \
    _Pragma("unroll")                                                                   \
    for (int nt = 0; nt < 4; ++nt) {                                                    \
      int kabs = k0 + nt * 16 + l16;                                                    \
      _Pragma("unroll")                                                                 \
      for (int r = 0; r < 4; ++r) {                                                     \
        float v = sacc[nt][r] * scale;                                                  \
        if (diag_) {                                                                    \
          int qabs = q0_ + wave * 16 + quad * 4 + r;                                    \
          if (kabs > qabs) v = NEG;                                                     \
        }                                                                               \
        p_[nt][r] = v;                                                                  \
        mt[r] = fmaxf(mt[r], v);                                                        \
      }                                                                                 \
    }                                                                                   \
    _Pragma("unroll")                                                                   \
    for (int off = 1; off < 16; off <<= 1)                                              \
      _Pragma("unroll")                                                                 \
      for (int r = 0; r < 4; ++r) mt[r] = fmaxf(mt[r], __shfl_xor(mt[r], off, 64));     \
    float dneed = mt[0] - m_run[0];                                                     \
    _Pragma("unroll")                                                                   \
    for (int r = 1; r < 4; ++r) dneed = fmaxf(dneed, mt[r] - m_run[r]);                 \
    if (!__all(dneed <= 8.0f)) {                                                        \
      _Pragma("unroll")                                                                 \
      for (int r = 0; r < 4; ++r) {                                                     \
        float mnew = fmaxf(m_run[r], mt[r]);                                            \
        float alpha = __expf(m_run[r] - mnew);                                          \
        m_run[r] = mnew;                                                                \
        l_run[r] *= alpha;                                                              \
        _Pragma("unroll")                                                               \
        for (int j = 0; j < 8; ++j) oacc[j][r] *= alpha;                                \
      }                                                                                 \
    }                                                                                   \
    float sums[4];                                                                      \
    _Pragma("unroll")                                                                   \
    for (int r = 0; r < 4; ++r) {                                                       \
      float s = 0.f;                                                                    \
      _Pragma("unroll")                                                                 \
      for (int nt = 0; nt < 4; ++nt) {                                                  \
        float e = __expf(p_[nt][r] - m_run[r]); p_[nt][r] = e; s += e;                  \
      }                                                                                 \
      sums[r] = s;                                                                      \
    }                                                                                   \
    _Pragma("unroll")                                                                   \
    for (int off = 1; off < 16; off <<= 1)                                              \
      _Pragma("unroll")                                                                 \
      for (int r = 0; r < 4; ++r) sums[r] += __shfl_xor(sums[r], off, 64);              \
    _Pragma("unroll")                                                                   \
    for (int r = 0; r < 4; ++r) l_run[r] += sums[r];                                    \
    _Pragma("unroll")                                                                   \
    for (int nt = 0; nt < 4; ++nt)                                                      \
      _Pragma("unroll")                                                                 \
      for (int r = 0; r < 4; ++r)                                                       \
        Plds[PH][wave][quad * 4 + r][nt * 16 + l16] = f2b(p_[nt][r]);                   \
    asm volatile("s_waitcnt lgkmcnt(0)" ::: "memory");                                  \
    __builtin_amdgcn_sched_barrier(0);                                                  \
    __builtin_amdgcn_s_setprio(1);                                                      \
    _Pragma("unroll")                                                                   \
    for (int s2 = 0; s2 < 2; ++s2) {                                                    \
      bf16x8_t ap = *reinterpret_cast<const bf16x8_t*>(                                 \
          &Plds[PH][wave][l16][s2 * 32 + quad * 8]);                                    \
      _Pragma("unroll")                                                                 \
      for (int j = 0; j < 8; ++j) {                                                     \
        int vd = j * 16 + l16;                                                          \
        int rot = ((vd >> 3) & 7) * 8;                                                  \
        int start = (s2 * 32 + quad * 8 + rot) & 63;                                    \
        bf16x8_t bv = *reinterpret_cast<const bf16x8_t*>(&Vlds[vd][start]);             \
        oacc[j] = __builtin_amdgcn_mfma_f32_16x16x32_bf16(ap, bv, oacc[j], 0, 0, 0);    \
      }                                                                                 \
    }                                                                                   \
    __builtin_amdgcn_s_setprio(0);                                                      \
  }

__global__ __launch_bounds__(256, 2) void attn_k(
    const short* __restrict__ q, const short* __restrict__ kv,
    const short* __restrict__ kpe, short* __restrict__ obuf) {
  const int h = blockIdx.y;
  const int qtA = blockIdx.x;        // 0..15
  const int qtB = 31 - qtA;          // 16..31 (qtA < qtB)
  const int tid = threadIdx.x, wave = tid >> 6, lane = tid & 63, quad = lane >> 4, l16 = lane & 15;
  const float scale = 0.072168784f;  // 1/sqrt(192)
  const float NEG = -1e30f;

  __shared__ __align__(16) short Klds[64][200];      // [krow][d 0..191 + 8 pad]
  __shared__ __align__(16) short Vlds[128][72];      // [vd][krow], krow rotated by vd>>3
  __shared__ __align__(16) short Plds[2][4][16][72]; // per-phase, per-wave P strip

  bf16x8_t aqA[6], aqB[6];
  {
    const size_t qrA = (size_t)(qtA * 64 + wave * 16 + l16) * (NH * 192) + (size_t)h * 192;
    const size_t qrB = (size_t)(qtB * 64 + wave * 16 + l16) * (NH * 192) + (size_t)h * 192;
#pragma unroll
    for (int s = 0; s < 6; ++s) {
      aqA[s] = *reinterpret_cast<const bf16x8_t*>(q + qrA + s * 32 + quad * 8);
      aqB[s] = *reinterpret_cast<const bf16x8_t*>(q + qrB + s * 32 + quad * 8);
    }
  }

  f32x4_t oaccA[8], oaccB[8];
  float mA[4], lA[4], mB[4], lB[4];
#pragma unroll
  for (int j = 0; j < 8; ++j) {
    oaccA[j][0] = 0.f; oaccA[j][1] = 0.f; oaccA[j][2] = 0.f; oaccA[j][3] = 0.f;
    oaccB[j][0] = 0.f; oaccB[j][1] = 0.f; oaccB[j][2] = 0.f; oaccB[j][3] = 0.f;
  }
#pragma unroll
  for (int r = 0; r < 4; ++r) { mA[r] = NEG; lA[r] = 0.f; mB[r] = NEG; lB[r] = 0.f; }

  for (int kt = 0; kt <= qtB; ++kt) {
    const int k0 = kt * 64;
    __syncthreads();   // prior iteration's LDS reads complete
    // stage K tile: 64 rows x 24 chunks (16 k_nope from kv + 8 from kpe), coalesced b128
#pragma unroll
    for (int i = 0; i < 6; ++i) {
      int c = tid + i * 256;              // 0..1535
      int krow = c / 24, sub = c - krow * 24;
      const short* src = (sub < 16)
          ? kv + (size_t)(k0 + krow) * (NH * 256) + (size_t)h * 256 + sub * 8
          : kpe + (size_t)(k0 + krow) * 64 + (sub - 16) * 8;
      *reinterpret_cast<bf16x8_t*>(&Klds[krow][sub * 8]) =
          *reinterpret_cast<const bf16x8_t*>(src);
    }
    // stage V transposed: Vlds[vd][rot(krow)] = kv[k0+krow][h*256+128+vd]
#pragma unroll
    for (int cc = 0; cc < 4; ++cc) {
      int c = tid + cc * 256;
      int krow = c >> 4, vd0 = (c & 15) * 8;
      bf16x8_t v = *reinterpret_cast<const bf16x8_t*>(
          kv + (size_t)(k0 + krow) * (NH * 256) + (size_t)h * 256 + 128 + vd0);
      int rot = (c & 7) * 8;
#pragma unroll
      for (int j = 0; j < 8; ++j) Vlds[vd0 + j][(krow + rot) & 63] = v[j];
    }
    __syncthreads();
    // long q-tile first, then short q-tile (same staged K/V tile)
    PROC(aqB, oaccB, mB, lB, qtB * 64, kt == qtB, 0);
    if (kt <= qtA) {
      PROC(aqA, oaccA, mA, lA, qtA * 64, kt == qtA, 1);
    }
  }

#pragma unroll
  for (int r = 0; r < 4; ++r) {
    int tB = qtB * 64 + wave * 16 + quad * 4 + r;
    int tA = qtA * 64 + wave * 16 + quad * 4 + r;
    float invB = 1.0f / lB[r];
    float invA = 1.0f / lA[r];
#pragma unroll
    for (int j = 0; j < 8; ++j) {
      obuf[(size_t)tB * (NH * 128) + (size_t)h * 128 + j * 16 + l16] = f2b(oaccB[j][r] * invB);
      obuf[(size_t)tA * (NH * 128) + (size_t)h * 128 + j * 16 + l16] = f2b(oaccA[j][r] * invA);
    }
  }
}

extern "C" void kernel_launch(void* const* d_in, const int* in_sizes, int n_in,
                              void* d_out, int out_size, void* d_ws, size_t ws_size,
                              hipStream_t stream) {
  const float* h     = (const float*)d_in[0];
  const int*   pos   = (const int*)d_in[1];
  const float* Wq_a  = (const float*)d_in[2];
  const float* gq    = (const float*)d_in[3];
  const float* Wq_b  = (const float*)d_in[4];
  const float* Wkv_a = (const float*)d_in[5];
  const float* bkva  = (const float*)d_in[6];
  const float* gkv   = (const float*)d_in[7];
  const float* Wkv_b = (const float*)d_in[8];
  const float* Wo    = (const float*)d_in[9];
  float* out = (float*)d_out;

  // Workspace overlay timeline (peak = 75,759,616 B, proven budget):
  //  P0: h_bf [0,20.97M)
  //  P1: Wcat [20.97M,42.60M) = WqaT rows 0..1535 + WkvaT rows 1536..2111
  //  P2: gemm_skb: part bf16 [2][2048][2112] [42.60M,59.90M)
  //  P3: kvnormrope_r -> kvn [73.40M,75.50M), kpe [75.50M,75.76M)
  //      rmsnorm1536_r -> qn [67.11M,73.40M)     (h_bf/Wcat/part dead after these)
  //  P4: WqbT [0,18.87M); gemm q2 -> qbuf [33.55M,58.72M); ropeq
  //  P5: WkvbT [58.72M,67.11M) (qn dead after q2); kvbuf [0,33.55M)
  //  P6: attn -> obuf [58.72M,75.50M) (WkvbT/kvn dead; kpe preserved at tail)
  //  P7: WoT [0,41.94M) (kvbuf/qbuf dead); out GEMM
  char* ws = (char*)d_ws;
  short* h_bf  = (short*)(ws);
  short* Wcat  = (short*)(ws + 20971520);
  short* part  = (short*)(ws + 42598400);
  short* qn    = (short*)(ws + 67108864);
  short* kvn   = (short*)(ws + 73400320);
  short* kpe   = (short*)(ws + 75497472);
  short* WqbT  = (short*)(ws);
  short* qbuf  = (short*)(ws + 33554432);
  short* WkvbT = (short*)(ws + 58720256);
  short* kvbuf = (short*)(ws);
  short* obuf  = (short*)(ws + 58720256);
  short* WoT   = (short*)(ws);

  dim3 blk(256);

  // P0: h -> bf16
  conv_full<<<dim3((unsigned)((2048LL * 640 + 255) / 256)), blk, 0, stream>>>(h, h_bf, 2048LL * 640);

  // P1: concatenated transposed weights for the fused q1+latent GEMM
  tconv<<<dim3(24, 80), blk, 0, stream>>>(Wq_a, Wcat, 5120, 1536);
  tconv<<<dim3(9, 80), blk, 0, stream>>>(Wkv_a, Wcat + (size_t)1536 * 5120, 5120, 576);

  // P2: fused q1+latent split-K GEMM, pure bf16, double-buffered staging
  gemm_skb<<<dim3(17, 16, 2), blk, 0, stream>>>(h_bf, Wcat, part, 2048, 2112, 5120, 2560);

  // P3: reducers (+bias/norm/rope fused)
  kvnormrope_r<<<2048, blk, 0, stream>>>(part, bkva, gkv, pos, kvn, kpe);
  rmsnorm1536_r<<<2048, blk, 0, stream>>>(part, gq, qn);

  // P4: q2 as ONE GEMM over N=6144
  tconv<<<dim3(96, 24), blk, 0, stream>>>(Wq_b, WqbT, 1536, 6144);
  gemm_btt<false><<<dim3(48, 16), blk, 0, stream>>>(qn, WqbT, qbuf, 2048, 6144, 1536, 6144);
  ropeq<<<8192, blk, 0, stream>>>(qbuf, pos);

  // P5: kv_b path
  tconv<<<dim3(128, 8), blk, 0, stream>>>(Wkv_b, WkvbT, 512, 8192);
  gemm_btt<false><<<dim3(64, 16), blk, 0, stream>>>(kvn, WkvbT, kvbuf, 2048, 8192, 512, 8192);

  // P6: attention (balanced causal pairing, 512 equal-work blocks)
  attn_k<<<dim3(16, 32), blk, 0, stream>>>(qbuf, kvbuf, kpe, obuf);

  // P7: output projection
  tconv<<<dim3(80, 64), blk, 0, stream>>>(Wo, WoT, 4096, 5120);
  gemm_btt<true><<<dim3(40, 16), blk, 0, stream>>>(obuf, WoT, out, 2048, 5120, 4096, 5120);
}

// Round 10
// 619.827 us; speedup vs baseline: 1.1150x; 1.1150x over previous
//
#include <hip/hip_runtime.h>
#include <cstddef>

#define NH 32
#define TSEQ 2048

typedef short bf16x8_t __attribute__((ext_vector_type(8)));
typedef float f32x4_t  __attribute__((ext_vector_type(4)));

__device__ __forceinline__ float b2f(short u) {
  unsigned v = ((unsigned)(unsigned short)u) << 16;
  return __builtin_bit_cast(float, v);
}
__device__ __forceinline__ short f2b(float f) {
  unsigned u = __builtin_bit_cast(unsigned, f);
  u = u + 0x7fffu + ((u >> 16) & 1u);   // RNE; inputs never NaN/Inf here
  return (short)(u >> 16);
}

// async global->LDS, 16B per lane; LDS dest is wave-uniform (HW writes base + lane*16)
__device__ __forceinline__ void gload16(const short* g, short* l) {
  __builtin_amdgcn_global_load_lds(
      (const __attribute__((address_space(1))) void*)g,
      (__attribute__((address_space(3))) void*)l, 16, 0, 0);
}

// ------------- fp32 -> bf16 row-major convert (for h) ---------------------------------
__global__ __launch_bounds__(256) void conv_full(
    const float* __restrict__ in, short* __restrict__ out, long long n8) {
  long long g = (long long)blockIdx.x * 256 + threadIdx.x;
  if (g >= n8) return;
  const float* p = in + g * 8;
  float4 a = *reinterpret_cast<const float4*>(p);
  float4 b = *reinterpret_cast<const float4*>(p + 4);
  bf16x8_t v;
  v[0] = f2b(a.x); v[1] = f2b(a.y); v[2] = f2b(a.z); v[3] = f2b(a.w);
  v[4] = f2b(b.x); v[5] = f2b(b.y); v[6] = f2b(b.z); v[7] = f2b(b.w);
  *reinterpret_cast<bf16x8_t*>(out + g * 8) = v;
}

// ------------- fused transpose + fp32->bf16: in[R][ldin] (submatrix R x C) -> out[C][R]
__global__ __launch_bounds__(256) void tconv(
    const float* __restrict__ in, short* __restrict__ out, int R, int ldin) {
  __shared__ short tile[64][72];
  const int tid = threadIdx.x;
  const int c0 = blockIdx.x * 64, r0 = blockIdx.y * 64;
#pragma unroll
  for (int cc = 0; cc < 2; ++cc) {
    int idx = tid + cc * 256;
    int row = idx >> 3, col = (idx & 7) * 8;
    const float* p = in + (size_t)(r0 + row) * ldin + c0 + col;
    float4 a = *reinterpret_cast<const float4*>(p);
    float4 b = *reinterpret_cast<const float4*>(p + 4);
    short* t = &tile[row][col];
    t[0] = f2b(a.x); t[1] = f2b(a.y); t[2] = f2b(a.z); t[3] = f2b(a.w);
    t[4] = f2b(b.x); t[5] = f2b(b.y); t[6] = f2b(b.z); t[7] = f2b(b.w);
  }
  __syncthreads();
#pragma unroll
  for (int cc = 0; cc < 2; ++cc) {
    int idx = tid + cc * 256;
    int orow = idx >> 3, ocol = (idx & 7) * 8;
    bf16x8_t v;
#pragma unroll
    for (int j = 0; j < 8; ++j) v[j] = tile[ocol + j][orow];
    *reinterpret_cast<bf16x8_t*>(out + (size_t)(c0 + orow) * R + r0 + ocol) = v;
  }
}

// ---------------- GEMM: C[M][ldc] = A[M][K] * Bt[N][K]^T, bf16 in, bf16/f32 out -------
// ROUND-8 VERIFIED FORM (round-9 dbuf reverted: 64KB LDS halved blocks/CU, m132-style
// occupancy loss outweighed pipeline gain). Single 32KB buffer, 2 barriers/iter,
// global_load_lds dwordx4 with XOR-swizzled source slot + same XOR on fragment read.
template <bool F32OUT>
__global__ __launch_bounds__(256) void gemm_btt(
    const short* __restrict__ A, const short* __restrict__ Bt,
    void* __restrict__ Cv, int M, int N, int K, int ldc) {
  __shared__ __align__(16) short Alds[128][64];
  __shared__ __align__(16) short Blds[128][64];
  const int tid = threadIdx.x;
  const int wave = tid >> 6, lane = tid & 63, quad = lane >> 4, l16 = lane & 15;
  const int m0 = blockIdx.y * 128, n0 = blockIdx.x * 128;
  const int wm = (wave >> 1) * 64, wn = (wave & 1) * 64;
  const int lrow = lane >> 3;
  const int lcol = ((lane ^ lrow) & 7) * 8;   // XOR-swizzled source slot (shorts)

  f32x4_t acc[4][4];
#pragma unroll
  for (int i = 0; i < 4; ++i)
#pragma unroll
    for (int j = 0; j < 4; ++j) {
      acc[i][j][0] = 0.f; acc[i][j][1] = 0.f; acc[i][j][2] = 0.f; acc[i][j][3] = 0.f;
    }

  for (int k0 = 0; k0 < K; k0 += 64) {
    __syncthreads();
#pragma unroll
    for (int c = 0; c < 4; ++c) {
      int chunk = wave + c * 4;          // 16 chunks of 8 rows x 128B
      int row = chunk * 8 + lrow;
      gload16(A + (size_t)(m0 + row) * K + k0 + lcol, &Alds[chunk * 8][0]);
      gload16(Bt + (size_t)(n0 + row) * K + k0 + lcol, &Blds[chunk * 8][0]);
    }
    __syncthreads();   // compiler drains vmcnt(0) before s_barrier
#pragma unroll
    for (int s = 0; s < 2; ++s) {
      bf16x8_t af[4], bfr[4];
#pragma unroll
      for (int i = 0; i < 4; ++i)
        af[i] = *reinterpret_cast<const bf16x8_t*>(
            &Alds[wm + i * 16 + l16][(((s * 4 + quad) ^ l16) & 7) * 8]);
#pragma unroll
      for (int j = 0; j < 4; ++j)
        bfr[j] = *reinterpret_cast<const bf16x8_t*>(
            &Blds[wn + j * 16 + l16][(((s * 4 + quad) ^ l16) & 7) * 8]);
#pragma unroll
      for (int i = 0; i < 4; ++i)
#pragma unroll
        for (int j = 0; j < 4; ++j)
          acc[i][j] = __builtin_amdgcn_mfma_f32_16x16x32_bf16(af[i], bfr[j], acc[i][j], 0, 0, 0);
    }
  }
#pragma unroll
  for (int j = 0; j < 4; ++j) {
    int col = n0 + wn + j * 16 + l16;
#pragma unroll
    for (int i = 0; i < 4; ++i) {
      int rowb = m0 + wm + i * 16 + quad * 4;
#pragma unroll
      for (int r = 0; r < 4; ++r) {
        if constexpr (F32OUT) {
          ((float*)Cv)[(size_t)(rowb + r) * ldc + col] = acc[i][j][r];
        } else {
          ((short*)Cv)[(size_t)(rowb + r) * ldc + col] = f2b(acc[i][j][r]);
        }
      }
    }
  }
}

// ------- split-K pure-bf16 GEMM (fused q1+latent): round-8 verified form --------------
// N=2112: last n-block's B rows OOB-read workspace garbage, epilogue-discarded.
__global__ __launch_bounds__(256) void gemm_skb(
    const short* __restrict__ A, const short* __restrict__ Bt,
    short* __restrict__ Cp, int M, int N, int K, int kchunk) {
  __shared__ __align__(16) short Alds[128][64];
  __shared__ __align__(16) short Blds[128][64];
  const int tid = threadIdx.x;
  const int wave = tid >> 6, lane = tid & 63, quad = lane >> 4, l16 = lane & 15;
  const int m0 = blockIdx.y * 128, n0 = blockIdx.x * 128;
  const int wm = (wave >> 1) * 64, wn = (wave & 1) * 64;
  const int lrow = lane >> 3;
  const int lcol = ((lane ^ lrow) & 7) * 8;
  const int kb = blockIdx.z * kchunk;

  f32x4_t acc[4][4];
#pragma unroll
  for (int i = 0; i < 4; ++i)
#pragma unroll
    for (int j = 0; j < 4; ++j) {
      acc[i][j][0] = 0.f; acc[i][j][1] = 0.f; acc[i][j][2] = 0.f; acc[i][j][3] = 0.f;
    }

  for (int k0 = kb; k0 < kb + kchunk; k0 += 64) {
    __syncthreads();
#pragma unroll
    for (int c = 0; c < 4; ++c) {
      int chunk = wave + c * 4;
      int row = chunk * 8 + lrow;
      gload16(A + (size_t)(m0 + row) * K + k0 + lcol, &Alds[chunk * 8][0]);
      gload16(Bt + (size_t)(n0 + row) * K + k0 + lcol, &Blds[chunk * 8][0]);
    }
    __syncthreads();
#pragma unroll
    for (int s = 0; s < 2; ++s) {
      bf16x8_t af[4], bfr[4];
#pragma unroll
      for (int i = 0; i < 4; ++i)
        af[i] = *reinterpret_cast<const bf16x8_t*>(
            &Alds[wm + i * 16 + l16][(((s * 4 + quad) ^ l16) & 7) * 8]);
#pragma unroll
      for (int j = 0; j < 4; ++j)
        bfr[j] = *reinterpret_cast<const bf16x8_t*>(
            &Blds[wn + j * 16 + l16][(((s * 4 + quad) ^ l16) & 7) * 8]);
#pragma unroll
      for (int i = 0; i < 4; ++i)
#pragma unroll
        for (int j = 0; j < 4; ++j)
          acc[i][j] = __builtin_amdgcn_mfma_f32_16x16x32_bf16(af[i], bfr[j], acc[i][j], 0, 0, 0);
    }
  }
  short* out = Cp + (size_t)blockIdx.z * M * N;
#pragma unroll
  for (int j = 0; j < 4; ++j) {
    int col = n0 + wn + j * 16 + l16;
    if (col >= N) continue;
#pragma unroll
    for (int i = 0; i < 4; ++i) {
      int rowb = m0 + wm + i * 16 + quad * 4;
#pragma unroll
      for (int r = 0; r < 4; ++r)
        out[(size_t)(rowb + r) * N + col] = f2b(acc[i][j][r]);
    }
  }
}

// ------- FUSED reducer: reduce-2 + q-RMSNorm (cols 0..1535) + bias/kv-RMSNorm (512)
// ------- + k_pe RoPE, one block per row (merges round-8's two reducer launches) -------
__global__ __launch_bounds__(256) void normrope_r(
    const short* __restrict__ part, const float* __restrict__ gq,
    const float* __restrict__ bkva, const float* __restrict__ gkv,
    const int* __restrict__ pos, short* __restrict__ qn,
    short* __restrict__ kvn, short* __restrict__ kpe) {
  const int t = blockIdx.x, tid = threadIdx.x;
  const size_t SL = (size_t)2048 * 2112;
  const short* row = part + (size_t)t * 2112;
  const short* rkv = row + 1536;
  // q half
  float v[6], ssq = 0.f;
#pragma unroll
  for (int i = 0; i < 6; ++i) {
    int col = tid + i * 256;
    v[i] = b2f(row[col]) + b2f(row[SL + col]);
    ssq += v[i] * v[i];
  }
  // kv half
  float v0 = bkva[tid] + b2f(rkv[tid]) + b2f(rkv[SL + tid]);
  float v1 = bkva[tid + 256] + b2f(rkv[tid + 256]) + b2f(rkv[SL + tid + 256]);
  float ssk = v0 * v0 + v1 * v1;
#pragma unroll
  for (int off = 1; off < 64; off <<= 1) {
    ssq += __shfl_xor(ssq, off, 64);
    ssk += __shfl_xor(ssk, off, 64);
  }
  __shared__ float redq[4], redk[4];
  if ((tid & 63) == 0) { redq[tid >> 6] = ssq; redk[tid >> 6] = ssk; }
  __syncthreads();
  float scq = rsqrtf((redq[0] + redq[1] + redq[2] + redq[3]) * (1.0f / 1536.0f) + 1e-6f);
  float sck = rsqrtf((redk[0] + redk[1] + redk[2] + redk[3]) * (1.0f / 512.0f) + 1e-6f);
#pragma unroll
  for (int i = 0; i < 6; ++i)
    qn[(size_t)t * 1536 + tid + i * 256] = f2b(v[i] * scq * gq[tid + i * 256]);
  kvn[(size_t)t * 512 + tid]       = f2b(v0 * sck * gkv[tid]);
  kvn[(size_t)t * 512 + tid + 256] = f2b(v1 * sck * gkv[tid + 256]);
  if (tid < 32) {
    float x1 = bkva[512 + 2 * tid] + b2f(rkv[512 + 2 * tid]) + b2f(rkv[SL + 512 + 2 * tid]);
    float x2 = bkva[513 + 2 * tid] + b2f(rkv[513 + 2 * tid]) + b2f(rkv[SL + 513 + 2 * tid]);
    float p = (float)pos[t];
    float inv = powf(10000.0f, -(float)tid / 32.0f);
    float f = p * inv;
    float sn = sinf(f), cs = cosf(f);
    kpe[(size_t)t * 64 + 2 * tid]     = f2b(x1 * cs - x2 * sn);
    kpe[(size_t)t * 64 + 2 * tid + 1] = f2b(x1 * sn + x2 * cs);
  }
}

// ---------------- in-place RoPE on q_pe slice of q [T][H*192] -------------------------
__global__ __launch_bounds__(256) void ropeq(short* __restrict__ q, const int* __restrict__ pos) {
  int idx = blockIdx.x * 256 + threadIdx.x;  // T*H*32 pairs
  int i = idx & 31, h = (idx >> 5) & 31, t = idx >> 10;
  size_t base = (size_t)t * 6144 + h * 192 + 128 + 2 * i;
  float x1 = b2f(q[base]), x2 = b2f(q[base + 1]);
  float p = (float)pos[t];
  float inv = powf(10000.0f, -(float)i / 32.0f);
  float f = p * inv;
  float sn = sinf(f), cs = cosf(f);
  q[base]     = f2b(x1 * cs - x2 * sn);
  q[base + 1] = f2b(x1 * sn + x2 * cs);
}

// ---------------- flash attention, balanced causal pairing ----------------------------
// round-10: row-sum of P via MFMA with all-ones B-fragment (2 extra MFMA/PROC) replaces
// the 16-lane shuffle reduce (~50 VALU ops) — attn is VALU-bound (30% vs 14% Mfma).
// l is now computed from the same bf16-rounded P that PV consumes (self-consistent).
// Keeps round-9's defer-max (THR=8).
#define PROC(aq, oacc, m_run, l_run, q0v, diagv, PH)                                    \
  {                                                                                     \
    const int q0_ = (q0v);                                                              \
    const bool diag_ = (diagv);                                                         \
    f32x4_t sacc[4];                                                                    \
    _Pragma("unroll")                                                                   \
    for (int nt = 0; nt < 4; ++nt) {                                                    \
      sacc[nt][0] = 0.f; sacc[nt][1] = 0.f; sacc[nt][2] = 0.f; sacc[nt][3] = 0.f;       \
    }                                                                                   \
    __builtin_amdgcn_s_setprio(1);                                                      \
    _Pragma("unroll")                                                                   \
    for (int nt = 0; nt < 4; ++nt) {                                                    \
      _Pragma("unroll")                                                                 \
      for (int s = 0; s < 6; ++s) {                                                     \
        bf16x8_t bk = *reinterpret_cast<const bf16x8_t*>(                               \
            &Klds[nt * 16 + l16][s * 32 + quad * 8]);                                   \
        sacc[nt] = __builtin_amdgcn_mfma_f32_16x16x32_bf16(aq[s], bk, sacc[nt], 0, 0, 0); \
      }                                                                                 \
    }                                                                                   \
    __builtin_amdgcn_s_setprio(0);                                                      \
    float p_[4][4], mt[4];                                                              \
    _Pragma("unroll")                                                                   \
    for (int r = 0; r < 4; ++r) mt[r] = NEG;                                            \
    _Pragma("unroll")                                                                   \
    for (int nt = 0; nt < 4; ++nt) {                                                    \
      int kabs = k0 + nt * 16 + l16;                                                    \
      _Pragma("unroll")                                                                 \
      for (int r = 0; r < 4; ++r) {                                                     \
        float v = sacc[nt][r] * scale;                                                  \
        if (diag_) {                                                                    \
          int qabs = q0_ + wave * 16 + quad * 4 + r;                                    \
          if (kabs > qabs) v = NEG;                                                     \
        }                                                                               \
        p_[nt][r] = v;                                                                  \
        mt[r] = fmaxf(mt[r], v);                                                        \
      }                                                                                 \
    }                                                                                   \
    _Pragma("unroll")                                                                   \
    for (int off = 1; off < 16; off <<= 1)                                              \
      _Pragma("unroll")                                                                 \
      for (int r = 0; r < 4; ++r) mt[r] = fmaxf(mt[r], __shfl_xor(mt[r], off, 64));     \
    float dneed = mt[0] - m_run[0];                                                     \
    _Pragma("unroll")                                                                   \
    for (int r = 1; r < 4; ++r) dneed = fmaxf(dneed, mt[r] - m_run[r]);                 \
    if (!__all(dneed <= 8.0f)) {                                                        \
      _Pragma("unroll")                                                                 \
      for (int r = 0; r < 4; ++r) {                                                     \
        float mnew = fmaxf(m_run[r], mt[r]);                                            \
        float alpha = __expf(m_run[r] - mnew);                                          \
        m_run[r] = mnew;                                                                \
        l_run[r] *= alpha;                                                              \
        _Pragma("unroll")                                                               \
        for (int j = 0; j < 8; ++j) oacc[j][r] *= alpha;                                \
      }                                                                                 \
    }                                                                                   \
    _Pragma("unroll")                                                                   \
    for (int r = 0; r < 4; ++r) {                                                       \
      _Pragma("unroll")                                                                 \
      for (int nt = 0; nt < 4; ++nt) p_[nt][r] = __expf(p_[nt][r] - m_run[r]);          \
    }                                                                                   \
    _Pragma("unroll")                                                                   \
    for (int nt = 0; nt < 4; ++nt)                                                      \
      _Pragma("unroll")                                                                 \
      for (int r = 0; r < 4; ++r)                                                       \
        Plds[PH][wave][quad * 4 + r][nt * 16 + l16] = f2b(p_[nt][r]);                   \
    asm volatile("s_waitcnt lgkmcnt(0)" ::: "memory");                                  \
    __builtin_amdgcn_sched_barrier(0);                                                  \
    f32x4_t lacc;                                                                       \
    lacc[0] = 0.f; lacc[1] = 0.f; lacc[2] = 0.f; lacc[3] = 0.f;                         \
    __builtin_amdgcn_s_setprio(1);                                                      \
    _Pragma("unroll")                                                                   \
    for (int s2 = 0; s2 < 2; ++s2) {                                                    \
      bf16x8_t ap = *reinterpret_cast<const bf16x8_t*>(                                 \
          &Plds[PH][wave][l16][s2 * 32 + quad * 8]);                                    \
      lacc = __builtin_amdgcn_mfma_f32_16x16x32_bf16(ap, vones, lacc, 0, 0, 0);         \
      _Pragma("unroll")                                                                 \
      for (int j = 0; j < 8; ++j) {                                                     \
        int vd = j * 16 + l16;                                                          \
        int rot = ((vd >> 3) & 7) * 8;                                                  \
        int start = (s2 * 32 + quad * 8 + rot) & 63;                                    \
        bf16x8_t bv = *reinterpret_cast<const bf16x8_t*>(&Vlds[vd][start]);             \
        oacc[j] = __builtin_amdgcn_mfma_f32_16x16x32_bf16(ap, bv, oacc[j], 0, 0, 0);    \
      }                                                                                 \
    }                                                                                   \
    __builtin_amdgcn_s_setprio(0);                                                      \
    _Pragma("unroll")                                                                   \
    for (int r = 0; r < 4; ++r) l_run[r] += lacc[r];                                    \
  }

__global__ __launch_bounds__(256, 2) void attn_k(
    const short* __restrict__ q, const short* __restrict__ kv,
    const short* __restrict__ kpe, short* __restrict__ obuf) {
  const int h = blockIdx.y;
  const int qtA = blockIdx.x;        // 0..15
  const int qtB = 31 - qtA;          // 16..31 (qtA < qtB)
  const int tid = threadIdx.x, wave = tid >> 6, lane = tid & 63, quad = lane >> 4, l16 = lane & 15;
  const float scale = 0.072168784f;  // 1/sqrt(192)
  const float NEG = -1e30f;

  __shared__ __align__(16) short Klds[64][200];      // [krow][d 0..191 + 8 pad]
  __shared__ __align__(16) short Vlds[128][72];      // [vd][krow], krow rotated by vd>>3
  __shared__ __align__(16) short Plds[2][4][16][72]; // per-phase, per-wave P strip

  bf16x8_t vones;
#pragma unroll
  for (int i = 0; i < 8; ++i) vones[i] = (short)0x3F80;  // bf16 1.0

  bf16x8_t aqA[6], aqB[6];
  {
    const size_t qrA = (size_t)(qtA * 64 + wave * 16 + l16) * (NH * 192) + (size_t)h * 192;
    const size_t qrB = (size_t)(qtB * 64 + wave * 16 + l16) * (NH * 192) + (size_t)h * 192;
#pragma unroll
    for (int s = 0; s < 6; ++s) {
      aqA[s] = *reinterpret_cast<const bf16x8_t*>(q + qrA + s * 32 + quad * 8);
      aqB[s] = *reinterpret_cast<const bf16x8_t*>(q + qrB + s * 32 + quad * 8);
    }
  }

  f32x4_t oaccA[8], oaccB[8];
  float mA[4], lA[4], mB[4], lB[4];
#pragma unroll
  for (int j = 0; j < 8; ++j) {
    oaccA[j][0] = 0.f; oaccA[j][1] = 0.f; oaccA[j][2] = 0.f; oaccA[j][3] = 0.f;
    oaccB[j][0] = 0.f; oaccB[j][1] = 0.f; oaccB[j][2] = 0.f; oaccB[j][3] = 0.f;
  }
#pragma unroll
  for (int r = 0; r < 4; ++r) { mA[r] = NEG; lA[r] = 0.f; mB[r] = NEG; lB[r] = 0.f; }

  for (int kt = 0; kt <= qtB; ++kt) {
    const int k0 = kt * 64;
    __syncthreads();   // prior iteration's LDS reads complete
    // stage K tile: 64 rows x 24 chunks (16 k_nope from kv + 8 from kpe), coalesced b128
#pragma unroll
    for (int i = 0; i < 6; ++i) {
      int c = tid + i * 256;              // 0..1535
      int krow = c / 24, sub = c - krow * 24;
      const short* src = (sub < 16)
          ? kv + (size_t)(k0 + krow) * (NH * 256) + (size_t)h * 256 + sub * 8
          : kpe + (size_t)(k0 + krow) * 64 + (sub - 16) * 8;
      *reinterpret_cast<bf16x8_t*>(&Klds[krow][sub * 8]) =
          *reinterpret_cast<const bf16x8_t*>(src);
    }
    // stage V transposed: Vlds[vd][rot(krow)] = kv[k0+krow][h*256+128+vd]
#pragma unroll
    for (int cc = 0; cc < 4; ++cc) {
      int c = tid + cc * 256;
      int krow = c >> 4, vd0 = (c & 15) * 8;
      bf16x8_t v = *reinterpret_cast<const bf16x8_t*>(
          kv + (size_t)(k0 + krow) * (NH * 256) + (size_t)h * 256 + 128 + vd0);
      int rot = (c & 7) * 8;
#pragma unroll
      for (int j = 0; j < 8; ++j) Vlds[vd0 + j][(krow + rot) & 63] = v[j];
    }
    __syncthreads();
    // long q-tile first, then short q-tile (same staged K/V tile)
    PROC(aqB, oaccB, mB, lB, qtB * 64, kt == qtB, 0);
    if (kt <= qtA) {
      PROC(aqA, oaccA, mA, lA, qtA * 64, kt == qtA, 1);
    }
  }

#pragma unroll
  for (int r = 0; r < 4; ++r) {
    int tB = qtB * 64 + wave * 16 + quad * 4 + r;
    int tA = qtA * 64 + wave * 16 + quad * 4 + r;
    float invB = 1.0f / lB[r];
    float invA = 1.0f / lA[r];
#pragma unroll
    for (int j = 0; j < 8; ++j) {
      obuf[(size_t)tB * (NH * 128) + (size_t)h * 128 + j * 16 + l16] = f2b(oaccB[j][r] * invB);
      obuf[(size_t)tA * (NH * 128) + (size_t)h * 128 + j * 16 + l16] = f2b(oaccA[j][r] * invA);
    }
  }
}

extern "C" void kernel_launch(void* const* d_in, const int* in_sizes, int n_in,
                              void* d_out, int out_size, void* d_ws, size_t ws_size,
                              hipStream_t stream) {
  const float* h     = (const float*)d_in[0];
  const int*   pos   = (const int*)d_in[1];
  const float* Wq_a  = (const float*)d_in[2];
  const float* gq    = (const float*)d_in[3];
  const float* Wq_b  = (const float*)d_in[4];
  const float* Wkv_a = (const float*)d_in[5];
  const float* bkva  = (const float*)d_in[6];
  const float* gkv   = (const float*)d_in[7];
  const float* Wkv_b = (const float*)d_in[8];
  const float* Wo    = (const float*)d_in[9];
  float* out = (float*)d_out;

  // Workspace overlay timeline (peak = 75,759,616 B, proven budget):
  //  P0: h_bf [0,20.97M)
  //  P1: Wcat [20.97M,42.60M) = WqaT rows 0..1535 + WkvaT rows 1536..2111
  //  P2: gemm_skb: part bf16 [2][2048][2112] [42.60M,59.90M)
  //  P3: normrope_r -> qn [67.11M,73.40M), kvn [73.40M,75.50M), kpe [75.50M,75.76M)
  //      (h_bf/Wcat/part dead after this)
  //  P4: WqbT [0,18.87M); gemm q2 -> qbuf [33.55M,58.72M); ropeq
  //  P5: WkvbT [58.72M,67.11M) (qn dead after q2); kvbuf [0,33.55M)
  //  P6: attn -> obuf [58.72M,75.50M) (WkvbT/kvn dead; kpe preserved at tail)
  //  P7: WoT [0,41.94M) (kvbuf/qbuf dead); out GEMM
  char* ws = (char*)d_ws;
  short* h_bf  = (short*)(ws);
  short* Wcat  = (short*)(ws + 20971520);
  short* part  = (short*)(ws + 42598400);
  short* qn    = (short*)(ws + 67108864);
  short* kvn   = (short*)(ws + 73400320);
  short* kpe   = (short*)(ws + 75497472);
  short* WqbT  = (short*)(ws);
  short* qbuf  = (short*)(ws + 33554432);
  short* WkvbT = (short*)(ws + 58720256);
  short* kvbuf = (short*)(ws);
  short* obuf  = (short*)(ws + 58720256);
  short* WoT   = (short*)(ws);

  dim3 blk(256);

  // P0: h -> bf16
  conv_full<<<dim3((unsigned)((2048LL * 640 + 255) / 256)), blk, 0, stream>>>(h, h_bf, 2048LL * 640);

  // P1: concatenated transposed weights for the fused q1+latent GEMM
  tconv<<<dim3(24, 80), blk, 0, stream>>>(Wq_a, Wcat, 5120, 1536);
  tconv<<<dim3(9, 80), blk, 0, stream>>>(Wkv_a, Wcat + (size_t)1536 * 5120, 5120, 576);

  // P2: fused q1+latent split-K GEMM, pure bf16 (round-8 verified form)
  gemm_skb<<<dim3(17, 16, 2), blk, 0, stream>>>(h_bf, Wcat, part, 2048, 2112, 5120, 2560);

  // P3: fused reducer (+bias/norm/rope), one launch
  normrope_r<<<2048, blk, 0, stream>>>(part, gq, bkva, gkv, pos, qn, kvn, kpe);

  // P4: q2 as ONE GEMM over N=6144
  tconv<<<dim3(96, 24), blk, 0, stream>>>(Wq_b, WqbT, 1536, 6144);
  gemm_btt<false><<<dim3(48, 16), blk, 0, stream>>>(qn, WqbT, qbuf, 2048, 6144, 1536, 6144);
  ropeq<<<8192, blk, 0, stream>>>(qbuf, pos);

  // P5: kv_b path
  tconv<<<dim3(128, 8), blk, 0, stream>>>(Wkv_b, WkvbT, 512, 8192);
  gemm_btt<false><<<dim3(64, 16), blk, 0, stream>>>(kvn, WkvbT, kvbuf, 2048, 8192, 512, 8192);

  // P6: attention (balanced causal pairing, 512 equal-work blocks)
  attn_k<<<dim3(16, 32), blk, 0, stream>>>(qbuf, kvbuf, kpe, obuf);

  // P7: output projection
  tconv<<<dim3(80, 64), blk, 0, stream>>>(Wo, WoT, 4096, 5120);
  gemm_btt<true><<<dim3(40, 16), blk, 0, stream>>>(obuf, WoT, out, 2048, 5120, 4096, 5120);
}